// Round 4
// baseline (124.429 us; speedup 1.0000x reference)
//
#include <hip/hip_runtime.h>
#include <math.h>

#define C 32
#define OUT_DIM 288

__device__ __forceinline__ float gelu_tanh(float x) {
    // jax.nn.gelu approximate=True
    float x3 = x * x * x;
    float t = tanhf(0.7978845608028654f * (x + 0.044715f * x3));
    return 0.5f * x * (1.0f + t);
}

// lane-broadcast via v_readlane (VALU/SGPR path, avoids ds-pipe)
__device__ __forceinline__ float rl(float v, int c) {
    return __int_as_float(__builtin_amdgcn_readlane(__float_as_int(v), c));
}

__global__ void hist_kernel(const int* __restrict__ recv, int E, int* __restrict__ counts) {
    int e = blockIdx.x * 256 + threadIdx.x;
    if (e < E) atomicAdd(&counts[recv[e]], 1);
}

// One-block scan, 1024 threads:
// offsets[i+1] = inclusive prefix, cursor[i] = exclusive prefix, offsets[0]=0
__global__ __launch_bounds__(1024) void scan_kernel(
    const int* __restrict__ counts, int* __restrict__ offsets,
    int* __restrict__ cursor, int n)
{
    __shared__ int wbase[17];
    __shared__ int wtot[16];
    const int tid = threadIdx.x;
    const int lane = tid & 63;
    const int wid = tid >> 6;
    const int chunk = (n + 1023) >> 10;
    const int base = tid * chunk;

    int sum = 0;
    for (int i = 0; i < chunk; ++i) {
        int idx = base + i;
        if (idx < n) sum += counts[idx];
    }
    int v = sum;
    for (int off = 1; off < 64; off <<= 1) {
        int u = __shfl_up(v, off, 64);
        if (lane >= off) v += u;
    }
    if (lane == 63) wtot[wid] = v;
    __syncthreads();
    if (tid == 0) {
        int acc = 0;
        for (int w2 = 0; w2 < 16; ++w2) { wbase[w2] = acc; acc += wtot[w2]; }
    }
    __syncthreads();
    int run = wbase[wid] + (v - sum);
    for (int i = 0; i < chunk; ++i) {
        int idx = base + i;
        if (idx < n) {
            int cv = counts[idx];
            cursor[idx] = run;
            run += cv;
            offsets[idx + 1] = run;
        }
    }
    if (tid == 0) offsets[0] = 0;
}

// Scatter + spherical-harmonic precompute: adj[p] = {shx, shy, shz, sender_bits}
__global__ void scatter_sh_kernel(const int* __restrict__ recv,
                                  const int* __restrict__ senders,
                                  const float* __restrict__ pos, int E,
                                  int* __restrict__ cursor, float4* __restrict__ adj) {
    int e = blockIdx.x * 256 + threadIdx.x;
    if (e < E) {
        const int r = recv[e];
        const int s = senders[e];
        const float rx = pos[r * 3 + 0] - pos[s * 3 + 0];
        const float ry = pos[r * 3 + 1] - pos[s * 3 + 1];
        const float rz = pos[r * 3 + 2] - pos[s * 3 + 2];
        const float nrm = sqrtf(rx * rx + ry * ry + rz * rz);
        const float f = 1.7320508075688772f / fmaxf(nrm, 1e-9f);  // sqrt(3)/|r|
        const int p = atomicAdd(&cursor[r], 1);
        adj[p] = make_float4(rx * f, ry * f, rz * f, __int_as_float(s));
    }
}

// Block = 4 waves = 2 nodes x 2 roles. Edge phase: role = portion (stride-4
// interleave with half split -> 4 gather chains). Linear phase: role 0 = 0e+2e,
// role 1 = 1o; W-columns in VGPRs, A-broadcast via v_readlane (no ds traffic,
// no divergent double-execution).
__global__ __launch_bounds__(256) void agg_node_kernel(
    const float* __restrict__ node0, const float* __restrict__ node1,
    const int* __restrict__ offsets, const float4* __restrict__ adj,
    const float* __restrict__ Wpre0, const float* __restrict__ Wpre1,
    const float* __restrict__ Wpre2,
    const float* __restrict__ Wpost0, const float* __restrict__ Wpost1,
    const float* __restrict__ Wpost2,
    const float* __restrict__ Wsc0, const float* __restrict__ Wsc1,
    float* __restrict__ out, int N)
{
    __shared__ float prt[2][2][13][32];  // [slot][role][arr][c] edge partials (pre-scaled)
    __shared__ float sxn[2][4][32];      // [slot][{x0,x1x,x1y,x1z}][c]

    const int tid  = threadIdx.x;
    const int wv   = tid >> 6;
    const int slot = wv >> 1;
    const int role = wv & 1;
    const int lane = tid & 63;
    const int half = lane >> 5;
    const int c    = lane & 31;
    const int node = blockIdx.x * 2 + slot;
    const bool valid = (node < N);

    const float S2 = 0.70710678118654752f;   // 1/sqrt(2)
    const float S6 = 0.40824829046386302f;   // 1/sqrt(6)
    const float INV_SQRT3 = 0.57735026918962576f;
    const float INV_DEN = 1.0f / 16.0f;

    float ax0 = 0.f, atp0 = 0.f;
    float ax1x = 0.f, ax1y = 0.f, ax1z = 0.f;
    float at1x = 0.f, at1y = 0.f, at1z = 0.f;
    float a2v0 = 0.f, a2v1 = 0.f, a2v2 = 0.f, a2v3 = 0.f, a2v4 = 0.f;

#define EDGE_ACC(A, X0, U1)                                                 \
    {                                                                       \
        const float shx = (A).x, shy = (A).y, shz = (A).z;                  \
        ax0 += (X0);                                                        \
        atp0 += (U1).x * shx + (U1).y * shy + (U1).z * shz;                 \
        ax1x += (U1).x; ax1y += (U1).y; ax1z += (U1).z;                     \
        at1x += (X0) * shx; at1y += (X0) * shy; at1z += (X0) * shz;         \
        a2v0 += S2 * ((U1).x * shy + (U1).y * shx);                         \
        a2v1 += S2 * ((U1).y * shz + (U1).z * shy);                         \
        a2v2 += S6 * (2.f * (U1).z * shz - (U1).x * shx - (U1).y * shy);    \
        a2v3 += S2 * ((U1).x * shz + (U1).z * shx);                         \
        a2v4 += S2 * ((U1).x * shx - (U1).y * shy);                         \
    }

    if (valid) {
        const int end = offsets[node + 1];
        int k = offsets[node] + role * 2 + half;   // stride 4
        while (k + 12 < end) {
            const float4 A0 = adj[k];
            const float4 A1 = adj[k + 4];
            const float4 A2 = adj[k + 8];
            const float4 A3 = adj[k + 12];
            const int b0 = __float_as_int(A0.w) * C + c;
            const int b1 = __float_as_int(A1.w) * C + c;
            const int b2 = __float_as_int(A2.w) * C + c;
            const int b3 = __float_as_int(A3.w) * C + c;
            const float q0 = node0[b0];
            const float q1 = node0[b1];
            const float q2 = node0[b2];
            const float q3 = node0[b3];
            const float3 u0 = *(const float3*)(node1 + b0 * 3);
            const float3 u1 = *(const float3*)(node1 + b1 * 3);
            const float3 u2 = *(const float3*)(node1 + b2 * 3);
            const float3 u3 = *(const float3*)(node1 + b3 * 3);
            EDGE_ACC(A0, q0, u0);
            EDGE_ACC(A1, q1, u1);
            EDGE_ACC(A2, q2, u2);
            EDGE_ACC(A3, q3, u3);
            k += 16;
        }
        while (k < end) {
            const float4 A0 = adj[k];
            const int b0 = __float_as_int(A0.w) * C + c;
            const float q0 = node0[b0];
            const float3 u0 = *(const float3*)(node1 + b0 * 3);
            EDGE_ACC(A0, q0, u0);
            k += 4;
        }
    }
#undef EDGE_ACC

    // combine halves (totals land in both halves)
    ax0  += __shfl_xor(ax0, 32, 64);
    atp0 += __shfl_xor(atp0, 32, 64);
    ax1x += __shfl_xor(ax1x, 32, 64);
    ax1y += __shfl_xor(ax1y, 32, 64);
    ax1z += __shfl_xor(ax1z, 32, 64);
    at1x += __shfl_xor(at1x, 32, 64);
    at1y += __shfl_xor(at1y, 32, 64);
    at1z += __shfl_xor(at1z, 32, 64);
    a2v0 += __shfl_xor(a2v0, 32, 64);
    a2v1 += __shfl_xor(a2v1, 32, 64);
    a2v2 += __shfl_xor(a2v2, 32, 64);
    a2v3 += __shfl_xor(a2v3, 32, 64);
    a2v4 += __shfl_xor(a2v4, 32, 64);

    if (half == 0) {
        float* p = &prt[slot][role][0][c];
        p[0 * 32]  = ax0 * INV_DEN;
        p[1 * 32]  = atp0 * (INV_DEN * INV_SQRT3);
        p[2 * 32]  = ax1x * INV_DEN;
        p[3 * 32]  = ax1y * INV_DEN;
        p[4 * 32]  = ax1z * INV_DEN;
        p[5 * 32]  = at1x * INV_DEN;
        p[6 * 32]  = at1y * INV_DEN;
        p[7 * 32]  = at1z * INV_DEN;
        p[8 * 32]  = a2v0 * INV_DEN;
        p[9 * 32]  = a2v1 * INV_DEN;
        p[10 * 32] = a2v2 * INV_DEN;
        p[11 * 32] = a2v3 * INV_DEN;
        p[12 * 32] = a2v4 * INV_DEN;
    } else if (role == 0) {
        float x0n = 0.f, x1nx = 0.f, x1ny = 0.f, x1nz = 0.f;
        if (valid) {
            x0n = node0[node * C + c];
            const int b = (node * C + c) * 3;
            x1nx = node1[b + 0]; x1ny = node1[b + 1]; x1nz = node1[b + 2];
        }
        sxn[slot][0][c] = x0n;
        sxn[slot][1][c] = x1nx;
        sxn[slot][2][c] = x1ny;
        sxn[slot][3][c] = x1nz;
    }
    __syncthreads();

    // ---------------- linear phase: W in VGPRs, readlane broadcasts ----------------
    const int d = c;
    float* po = out + (size_t)node * OUT_DIM;
    float w[64];

    if (role == 0) {
        // === 0e path ===
        const float a0a = prt[slot][0][0][d] + prt[slot][1][0][d];
        const float a0b = prt[slot][0][1][d] + prt[slot][1][1][d];
        const float x0  = sxn[slot][0][d];
#pragma unroll
        for (int j = 0; j < 64; ++j) w[j] = Wpre0[j * C + d];
        float s0 = 0.f, s1 = 0.f;
#pragma unroll
        for (int cc = 0; cc < 32; cc += 2) {
            s0 += rl(a0a, cc) * w[cc]     + rl(a0b, cc) * w[32 + cc];
            s1 += rl(a0a, cc + 1) * w[cc + 1] + rl(a0b, cc + 1) * w[33 + cc];
        }
        const float h0 = gelu_tanh(s0 + s1);
#pragma unroll
        for (int j = 0; j < 32; ++j) w[j] = Wpost0[j * C + d];
#pragma unroll
        for (int j = 0; j < 32; ++j) w[32 + j] = Wsc0[j * C + d];
        float t0 = 0.f, t1 = 0.f;
#pragma unroll
        for (int cc = 0; cc < 32; cc += 2) {
            t0 += rl(h0, cc) * w[cc]     + rl(x0, cc) * w[32 + cc];
            t1 += rl(h0, cc + 1) * w[cc + 1] + rl(x0, cc + 1) * w[33 + cc];
        }
        if (half == 0 && valid) po[d] = t0 + t1;

        // === 2e path ===
#pragma unroll
        for (int j = 0; j < 32; ++j) w[j] = Wpre2[j * C + d];
        float h2[5];
#pragma unroll
        for (int m = 0; m < 5; ++m) {
            const float am = prt[slot][0][8 + m][d] + prt[slot][1][8 + m][d];
            float u0 = 0.f, u1 = 0.f;
#pragma unroll
            for (int cc = 0; cc < 32; cc += 2) {
                u0 += rl(am, cc) * w[cc];
                u1 += rl(am, cc + 1) * w[cc + 1];
            }
            h2[m] = u0 + u1;
        }
#pragma unroll
        for (int j = 0; j < 32; ++j) w[j] = Wpost2[j * C + d];
#pragma unroll
        for (int m = 0; m < 5; ++m) {
            float u0 = 0.f, u1 = 0.f;
#pragma unroll
            for (int cc = 0; cc < 32; cc += 2) {
                u0 += rl(h2[m], cc) * w[cc];
                u1 += rl(h2[m], cc + 1) * w[cc + 1];
            }
            if (half == 0 && valid) po[128 + d * 5 + m] = u0 + u1;
        }
    } else {
        // === 1o path ===
#pragma unroll
        for (int j = 0; j < 64; ++j) w[j] = Wpre1[j * C + d];
        float h1[3];
#pragma unroll
        for (int i = 0; i < 3; ++i) {
            const float aa = prt[slot][0][2 + i][d] + prt[slot][1][2 + i][d];
            const float ab = prt[slot][0][5 + i][d] + prt[slot][1][5 + i][d];
            float u0 = 0.f, u1 = 0.f;
#pragma unroll
            for (int cc = 0; cc < 32; cc += 2) {
                u0 += rl(aa, cc) * w[cc]     + rl(ab, cc) * w[32 + cc];
                u1 += rl(aa, cc + 1) * w[cc + 1] + rl(ab, cc + 1) * w[33 + cc];
            }
            h1[i] = u0 + u1;
        }
#pragma unroll
        for (int j = 0; j < 32; ++j) w[j] = Wpost1[j * C + d];
#pragma unroll
        for (int j = 0; j < 32; ++j) w[32 + j] = Wsc1[j * C + d];
#pragma unroll
        for (int i = 0; i < 3; ++i) {
            const float xi = sxn[slot][1 + i][d];
            float u0 = 0.f, u1 = 0.f;
#pragma unroll
            for (int cc = 0; cc < 32; cc += 2) {
                u0 += rl(h1[i], cc) * w[cc]     + rl(xi, cc) * w[32 + cc];
                u1 += rl(h1[i], cc + 1) * w[cc + 1] + rl(xi, cc + 1) * w[33 + cc];
            }
            if (half == 0 && valid) po[32 + d * 3 + i] = u0 + u1;
        }
    }
}

extern "C" void kernel_launch(void* const* d_in, const int* in_sizes, int n_in,
                              void* d_out, int out_size, void* d_ws, size_t ws_size,
                              hipStream_t stream) {
    const float* node0   = (const float*)d_in[0];
    const float* node1   = (const float*)d_in[1];
    const float* pos     = (const float*)d_in[2];
    const int*   senders = (const int*)d_in[3];
    const int*   recv    = (const int*)d_in[4];
    const float* Wpre0   = (const float*)d_in[5];
    const float* Wpre1   = (const float*)d_in[6];
    const float* Wpre2   = (const float*)d_in[7];
    const float* Wpost0  = (const float*)d_in[8];
    const float* Wpost1  = (const float*)d_in[9];
    const float* Wpost2  = (const float*)d_in[10];
    const float* Wsc0    = (const float*)d_in[11];
    const float* Wsc1    = (const float*)d_in[12];
    float* out = (float*)d_out;

    const int N = in_sizes[2] / 3;
    const int E = in_sizes[3];

    int* counts   = (int*)d_ws;
    int* offsets  = counts + N;
    int* cursor   = offsets + (N + 1);
    size_t adj_off = ((size_t)(cursor + N - (int*)d_ws) * sizeof(int) + 15) & ~(size_t)15;
    float4* adj = (float4*)((char*)d_ws + adj_off);

    hipMemsetAsync(counts, 0, (size_t)N * sizeof(int), stream);
    hist_kernel<<<(E + 255) / 256, 256, 0, stream>>>(recv, E, counts);
    scan_kernel<<<1, 1024, 0, stream>>>(counts, offsets, cursor, N);
    scatter_sh_kernel<<<(E + 255) / 256, 256, 0, stream>>>(recv, senders, pos, E, cursor, adj);
    agg_node_kernel<<<(N + 1) / 2, 256, 0, stream>>>(
        node0, node1, offsets, adj,
        Wpre0, Wpre1, Wpre2, Wpost0, Wpost1, Wpost2, Wsc0, Wsc1,
        out, N);
}

// Round 5
// 103.066 us; speedup vs baseline: 1.2073x; 1.2073x over previous
//
#include <hip/hip_runtime.h>
#include <math.h>

#define C 32
#define OUT_DIM 288
#define AGG_S 416   // 13 arrays * 32 channels, node-major stride (floats)

__device__ __forceinline__ float gelu_tanh(float x) {
    // jax.nn.gelu approximate=True
    float x3 = x * x * x;
    float t = tanhf(0.7978845608028654f * (x + 0.044715f * x3));
    return 0.5f * x * (1.0f + t);
}

// broadcast lane (32-group-local) c via ds_swizzle imm pattern: and=0, or=c, xor=0
#define BSW(v, c) __int_as_float(__builtin_amdgcn_ds_swizzle(__float_as_int(v), ((c) << 5)))

#define R32(M, ...)                                                          \
    M(0, __VA_ARGS__)  M(1, __VA_ARGS__)  M(2, __VA_ARGS__)  M(3, __VA_ARGS__)  \
    M(4, __VA_ARGS__)  M(5, __VA_ARGS__)  M(6, __VA_ARGS__)  M(7, __VA_ARGS__)  \
    M(8, __VA_ARGS__)  M(9, __VA_ARGS__)  M(10, __VA_ARGS__) M(11, __VA_ARGS__) \
    M(12, __VA_ARGS__) M(13, __VA_ARGS__) M(14, __VA_ARGS__) M(15, __VA_ARGS__) \
    M(16, __VA_ARGS__) M(17, __VA_ARGS__) M(18, __VA_ARGS__) M(19, __VA_ARGS__) \
    M(20, __VA_ARGS__) M(21, __VA_ARGS__) M(22, __VA_ARGS__) M(23, __VA_ARGS__) \
    M(24, __VA_ARGS__) M(25, __VA_ARGS__) M(26, __VA_ARGS__) M(27, __VA_ARGS__) \
    M(28, __VA_ARGS__) M(29, __VA_ARGS__) M(30, __VA_ARGS__) M(31, __VA_ARGS__)

// acc += bsw(AV,c)*w[c]          (single 32-term dot)
#define T1(c, ACC, AV) ACC = fmaf(BSW(AV, c), w[c], ACC);
// acc += bsw(AV1,c)*w[c] + bsw(AV2,c)*w[32+c]   (64-term dot, two sources)
#define T2(c, ACC, AV1, AV2) \
    ACC = fmaf(BSW(AV1, c), w[c], fmaf(BSW(AV2, c), w[32 + (c)], ACC));

__global__ void hist_kernel(const int* __restrict__ recv, int E, int* __restrict__ counts) {
    int e = blockIdx.x * 256 + threadIdx.x;
    if (e < E) atomicAdd(&counts[recv[e]], 1);
}

// One-block scan, 1024 threads:
// offsets[i+1] = inclusive prefix, cursor[i] = exclusive prefix, offsets[0]=0
__global__ __launch_bounds__(1024) void scan_kernel(
    const int* __restrict__ counts, int* __restrict__ offsets,
    int* __restrict__ cursor, int n)
{
    __shared__ int wbase[17];
    __shared__ int wtot[16];
    const int tid = threadIdx.x;
    const int lane = tid & 63;
    const int wid = tid >> 6;
    const int chunk = (n + 1023) >> 10;
    const int base = tid * chunk;

    int sum = 0;
    for (int i = 0; i < chunk; ++i) {
        int idx = base + i;
        if (idx < n) sum += counts[idx];
    }
    int v = sum;
    for (int off = 1; off < 64; off <<= 1) {
        int u = __shfl_up(v, off, 64);
        if (lane >= off) v += u;
    }
    if (lane == 63) wtot[wid] = v;
    __syncthreads();
    if (tid == 0) {
        int acc = 0;
        for (int w2 = 0; w2 < 16; ++w2) { wbase[w2] = acc; acc += wtot[w2]; }
    }
    __syncthreads();
    int run = wbase[wid] + (v - sum);
    for (int i = 0; i < chunk; ++i) {
        int idx = base + i;
        if (idx < n) {
            int cv = counts[idx];
            cursor[idx] = run;
            run += cv;
            offsets[idx + 1] = run;
        }
    }
    if (tid == 0) offsets[0] = 0;
}

// Scatter + spherical-harmonic precompute: adj[p] = {shx, shy, shz, sender_bits}
__global__ void scatter_sh_kernel(const int* __restrict__ recv,
                                  const int* __restrict__ senders,
                                  const float* __restrict__ pos, int E,
                                  int* __restrict__ cursor, float4* __restrict__ adj) {
    int e = blockIdx.x * 256 + threadIdx.x;
    if (e < E) {
        const int r = recv[e];
        const int s = senders[e];
        const float rx = pos[r * 3 + 0] - pos[s * 3 + 0];
        const float ry = pos[r * 3 + 1] - pos[s * 3 + 1];
        const float rz = pos[r * 3 + 2] - pos[s * 3 + 2];
        const float nrm = sqrtf(rx * rx + ry * ry + rz * rz);
        const float f = 1.7320508075688772f / fmaxf(nrm, 1e-9f);  // sqrt(3)/|r|
        const int p = atomicAdd(&cursor[r], 1);
        adj[p] = make_float4(rx * f, ry * f, rz * f, __int_as_float(s));
    }
}

// K1: 1 wave per node, no LDS. Halves process interleaved edges with a 2-edge
// unroll -> 4 gather chains in flight. Aggregates (pre-scaled by 1/DEN) are
// written node-major, coalesced: agg[node*416 + j*32 + c], j=0..12:
//  0: a0a  1: a0b(*1/sqrt3)  2..4: a1a  5..7: a1b  8..12: a2
__global__ __launch_bounds__(256) void edge_agg_kernel(
    const float* __restrict__ node0, const float* __restrict__ node1,
    const int* __restrict__ offsets, const float4* __restrict__ adj,
    float* __restrict__ agg, int N)
{
    const int tid  = threadIdx.x;
    const int wv   = tid >> 6;
    const int lane = tid & 63;
    const int half = lane >> 5;
    const int c    = lane & 31;
    const int node = blockIdx.x * 4 + wv;
    const bool valid = (node < N);

    const float S2 = 0.70710678118654752f;   // 1/sqrt(2)
    const float S6 = 0.40824829046386302f;   // 1/sqrt(6)
    const float INV_SQRT3 = 0.57735026918962576f;
    const float INV_DEN = 1.0f / 16.0f;

    float ax0 = 0.f, atp0 = 0.f;
    float ax1x = 0.f, ax1y = 0.f, ax1z = 0.f;
    float at1x = 0.f, at1y = 0.f, at1z = 0.f;
    float a2v0 = 0.f, a2v1 = 0.f, a2v2 = 0.f, a2v3 = 0.f, a2v4 = 0.f;

#define EDGE_ACC(A, X0, U1)                                                 \
    {                                                                       \
        const float shx = (A).x, shy = (A).y, shz = (A).z;                  \
        ax0 += (X0);                                                        \
        atp0 += (U1).x * shx + (U1).y * shy + (U1).z * shz;                 \
        ax1x += (U1).x; ax1y += (U1).y; ax1z += (U1).z;                     \
        at1x += (X0) * shx; at1y += (X0) * shy; at1z += (X0) * shz;         \
        a2v0 += S2 * ((U1).x * shy + (U1).y * shx);                         \
        a2v1 += S2 * ((U1).y * shz + (U1).z * shy);                         \
        a2v2 += S6 * (2.f * (U1).z * shz - (U1).x * shx - (U1).y * shy);    \
        a2v3 += S2 * ((U1).x * shz + (U1).z * shx);                         \
        a2v4 += S2 * ((U1).x * shx - (U1).y * shy);                         \
    }

    if (valid) {
        const int end = offsets[node + 1];
        int k = offsets[node] + half;   // this half's edges: k, k+2, ...
        while (k + 2 < end) {
            const float4 A0 = adj[k];
            const float4 A1 = adj[k + 2];
            const int b0 = __float_as_int(A0.w) * C + c;
            const int b1 = __float_as_int(A1.w) * C + c;
            const float q0 = node0[b0];
            const float q1 = node0[b1];
            const float3 u0 = *(const float3*)(node1 + b0 * 3);
            const float3 u1 = *(const float3*)(node1 + b1 * 3);
            EDGE_ACC(A0, q0, u0);
            EDGE_ACC(A1, q1, u1);
            k += 4;
        }
        if (k < end) {
            const float4 A0 = adj[k];
            const int b0 = __float_as_int(A0.w) * C + c;
            const float q0 = node0[b0];
            const float3 u0 = *(const float3*)(node1 + b0 * 3);
            EDGE_ACC(A0, q0, u0);
        }
    }
#undef EDGE_ACC

    // combine halves (totals land in both halves)
    ax0  += __shfl_xor(ax0, 32, 64);
    atp0 += __shfl_xor(atp0, 32, 64);
    ax1x += __shfl_xor(ax1x, 32, 64);
    ax1y += __shfl_xor(ax1y, 32, 64);
    ax1z += __shfl_xor(ax1z, 32, 64);
    at1x += __shfl_xor(at1x, 32, 64);
    at1y += __shfl_xor(at1y, 32, 64);
    at1z += __shfl_xor(at1z, 32, 64);
    a2v0 += __shfl_xor(a2v0, 32, 64);
    a2v1 += __shfl_xor(a2v1, 32, 64);
    a2v2 += __shfl_xor(a2v2, 32, 64);
    a2v3 += __shfl_xor(a2v3, 32, 64);
    a2v4 += __shfl_xor(a2v4, 32, 64);

    if (valid) {
        float* ag = agg + (size_t)node * AGG_S + c;
        const float v0 = ax0 * INV_DEN;
        const float v1 = atp0 * (INV_DEN * INV_SQRT3);
        const float v2 = ax1x * INV_DEN, v3 = ax1y * INV_DEN, v4 = ax1z * INV_DEN;
        const float v5 = at1x * INV_DEN, v6 = at1y * INV_DEN, v7 = at1z * INV_DEN;
        const float v8 = a2v0 * INV_DEN, v9 = a2v1 * INV_DEN, v10 = a2v2 * INV_DEN;
        const float v11 = a2v3 * INV_DEN, v12 = a2v4 * INV_DEN;
        if (half == 0) {
            ag[0 * 32] = v0;  ag[1 * 32] = v1;  ag[2 * 32] = v2;
            ag[3 * 32] = v3;  ag[4 * 32] = v4;  ag[5 * 32] = v5;
            ag[6 * 32] = v6;
        } else {
            ag[7 * 32] = v7;  ag[8 * 32] = v8;  ag[9 * 32] = v9;
            ag[10 * 32] = v10; ag[11 * 32] = v11; ag[12 * 32] = v12;
        }
    }
}

// K2: node-update GEMM. Wave = 2 nodes (half = node), d = lane&31 = output ch.
// W columns in w[64] VGPRs (shared by halves), A broadcast via ds_swizzle imm.
__global__ __launch_bounds__(256) void node_gemm_kernel(
    const float* __restrict__ node0, const float* __restrict__ node1,
    const float* __restrict__ agg,
    const float* __restrict__ Wpre0, const float* __restrict__ Wpre1,
    const float* __restrict__ Wpre2,
    const float* __restrict__ Wpost0, const float* __restrict__ Wpost1,
    const float* __restrict__ Wpost2,
    const float* __restrict__ Wsc0, const float* __restrict__ Wsc1,
    float* __restrict__ out, int N)
{
    const int tid  = threadIdx.x;
    const int wv   = tid >> 6;
    const int lane = tid & 63;
    const int half = lane >> 5;
    const int d    = lane & 31;
    const int n    = blockIdx.x * 8 + wv * 2 + half;
    const bool valid = (n < N);
    const int nn   = valid ? n : (N - 1);

    // A registers: a[j] holds agg[nn][j][d] (per-lane channel = d)
    float a[13];
#pragma unroll
    for (int j = 0; j < 13; ++j) a[j] = agg[(size_t)nn * AGG_S + j * 32 + d];
    const float x0 = node0[nn * C + d];
    const int xb = (nn * C + d) * 3;
    const float x1x = node1[xb + 0];
    const float x1y = node1[xb + 1];
    const float x1z = node1[xb + 2];

    float w[64];
    float* po = out + (size_t)n * OUT_DIM;

    // ---------- 1o path ----------
#pragma unroll
    for (int j = 0; j < 64; ++j) w[j] = Wpre1[j * C + d];
    float h1x = 0.f, h1y = 0.f, h1z = 0.f;
    R32(T2, h1x, a[2], a[5])
    R32(T2, h1y, a[3], a[6])
    R32(T2, h1z, a[4], a[7])
#pragma unroll
    for (int j = 0; j < 32; ++j) w[j] = Wpost1[j * C + d];
#pragma unroll
    for (int j = 0; j < 32; ++j) w[32 + j] = Wsc1[j * C + d];
    float o1x = 0.f, o1y = 0.f, o1z = 0.f;
    R32(T2, o1x, h1x, x1x)
    R32(T2, o1y, h1y, x1y)
    R32(T2, o1z, h1z, x1z)
    if (valid) {
        po[32 + d * 3 + 0] = o1x;
        po[32 + d * 3 + 1] = o1y;
        po[32 + d * 3 + 2] = o1z;
    }

    // ---------- 0e path ----------
#pragma unroll
    for (int j = 0; j < 64; ++j) w[j] = Wpre0[j * C + d];
    float h0 = 0.f;
    R32(T2, h0, a[0], a[1])
    h0 = gelu_tanh(h0);
#pragma unroll
    for (int j = 0; j < 32; ++j) w[j] = Wpost0[j * C + d];
#pragma unroll
    for (int j = 0; j < 32; ++j) w[32 + j] = Wsc0[j * C + d];
    float o0 = 0.f;
    R32(T2, o0, h0, x0)
    if (valid) po[d] = o0;

    // ---------- 2e path ----------
#pragma unroll
    for (int j = 0; j < 32; ++j) w[j] = Wpre2[j * C + d];
    float h20 = 0.f, h21 = 0.f, h22 = 0.f, h23 = 0.f, h24 = 0.f;
    R32(T1, h20, a[8])
    R32(T1, h21, a[9])
    R32(T1, h22, a[10])
    R32(T1, h23, a[11])
    R32(T1, h24, a[12])
#pragma unroll
    for (int j = 0; j < 32; ++j) w[j] = Wpost2[j * C + d];
    float o20 = 0.f, o21 = 0.f, o22 = 0.f, o23 = 0.f, o24 = 0.f;
    R32(T1, o20, h20)
    R32(T1, o21, h21)
    R32(T1, o22, h22)
    R32(T1, o23, h23)
    R32(T1, o24, h24)
    if (valid) {
        po[128 + d * 5 + 0] = o20;
        po[128 + d * 5 + 1] = o21;
        po[128 + d * 5 + 2] = o22;
        po[128 + d * 5 + 3] = o23;
        po[128 + d * 5 + 4] = o24;
    }
}

extern "C" void kernel_launch(void* const* d_in, const int* in_sizes, int n_in,
                              void* d_out, int out_size, void* d_ws, size_t ws_size,
                              hipStream_t stream) {
    const float* node0   = (const float*)d_in[0];
    const float* node1   = (const float*)d_in[1];
    const float* pos     = (const float*)d_in[2];
    const int*   senders = (const int*)d_in[3];
    const int*   recv    = (const int*)d_in[4];
    const float* Wpre0   = (const float*)d_in[5];
    const float* Wpre1   = (const float*)d_in[6];
    const float* Wpre2   = (const float*)d_in[7];
    const float* Wpost0  = (const float*)d_in[8];
    const float* Wpost1  = (const float*)d_in[9];
    const float* Wpost2  = (const float*)d_in[10];
    const float* Wsc0    = (const float*)d_in[11];
    const float* Wsc1    = (const float*)d_in[12];
    float* out = (float*)d_out;

    const int N = in_sizes[2] / 3;
    const int E = in_sizes[3];

    int* counts   = (int*)d_ws;
    int* offsets  = counts + N;
    int* cursor   = offsets + (N + 1);
    size_t adj_off = ((size_t)(cursor + N - (int*)d_ws) * sizeof(int) + 15) & ~(size_t)15;
    float4* adj = (float4*)((char*)d_ws + adj_off);
    float* agg = (float*)((char*)d_ws + adj_off + (size_t)E * sizeof(float4));

    hipMemsetAsync(counts, 0, (size_t)N * sizeof(int), stream);
    hist_kernel<<<(E + 255) / 256, 256, 0, stream>>>(recv, E, counts);
    scan_kernel<<<1, 1024, 0, stream>>>(counts, offsets, cursor, N);
    scatter_sh_kernel<<<(E + 255) / 256, 256, 0, stream>>>(recv, senders, pos, E, cursor, adj);
    edge_agg_kernel<<<(N + 3) / 4, 256, 0, stream>>>(node0, node1, offsets, adj, agg, N);
    node_gemm_kernel<<<(N + 7) / 8, 256, 0, stream>>>(
        node0, node1, agg,
        Wpre0, Wpre1, Wpre2, Wpost0, Wpost1, Wpost2, Wsc0, Wsc1,
        out, N);
}